// Round 7
// baseline (536.393 us; speedup 1.0000x reference)
//
#include <hip/hip_runtime.h>
#include <hip/hip_bf16.h>

// Problem constants (fixed by reference)
constexpr int NN = 100000;   // nodes
constexpr int NE = 3200000;  // edges
constexpr int NWG = 256;               // chunks for count/place
constexpr int CHUNK = NE / NWG;        // 12500 edges per WG
constexpr int CHUNK4 = CHUNK / 4;      // 3125 int4s per WG
constexpr int ROWS_B = 256;            // rows per coarse bucket
constexpr int NBUK1 = (NN + ROWS_B - 1) / ROWS_B;  // 391 coarse buckets (rows >> 8)
constexpr int SORT_CAP = 9216;         // LDS staging cap (avg 8192, sigma~90)

__device__ __forceinline__ unsigned short f2bf(float f) {
    unsigned int u = __float_as_uint(f);
    unsigned int r = (u + 0x7fffu + ((u >> 16) & 1u)) >> 16;   // RNE
    return (unsigned short)r;
}

// ---------------- GEMM1: xw1 = bf16(x @ W1)  [NN,128]x[128,128] ----------------
__global__ __launch_bounds__(256) void k_gemm1(const float* __restrict__ x,
                                               const float* __restrict__ W,
                                               unsigned short* __restrict__ y) {
    __shared__ float ws_[128 * 128];   // 64 KB: whole W1
    __shared__ float xs[8][128];       // 8 staged rows
    const int t = threadIdx.x;
    for (int i = t; i < 128 * 128; i += 256) ws_[i] = W[i];

    const int rowg = t >> 5;          // 0..7 (row within sub-tile)
    const int cq   = (t & 31) * 4;    // 4 output cols
    const int row0 = blockIdx.x * 32;

    for (int rs = 0; rs < 32; rs += 8) {
        __syncthreads();
        {   // stage 8 rows (1024 floats) as 256 float4s
            const int r  = t >> 5;
            const int c4 = (t & 31) * 4;
            const int row = row0 + rs + r;
            float4 val = (row < NN) ? *(const float4*)(x + row * 128 + c4)
                                    : make_float4(0.f, 0.f, 0.f, 0.f);
            *(float4*)(&xs[r][c4]) = val;
        }
        __syncthreads();
        float4 acc = make_float4(0.f, 0.f, 0.f, 0.f);
#pragma unroll
        for (int k = 0; k < 128; ++k) {
            const float xv = xs[rowg][k];
            const float4 wv = *(const float4*)(&ws_[k * 128 + cq]);
            acc.x = fmaf(xv, wv.x, acc.x);
            acc.y = fmaf(xv, wv.y, acc.y);
            acc.z = fmaf(xv, wv.z, acc.z);
            acc.w = fmaf(xv, wv.w, acc.w);
        }
        const int row = row0 + rs + rowg;
        if (row < NN) {
            ushort4 o;
            o.x = f2bf(acc.x); o.y = f2bf(acc.y);
            o.z = f2bf(acc.z); o.w = f2bf(acc.w);
            *(ushort4*)(y + row * 128 + cq) = o;   // 8B store
        }
    }
}

// ---------------- CSR build: WG-exclusive counting sort ----------------
// coarse bucket = row >> 8 (256 rows). tmp record: x = (lrow<<17)|col, y = val.

// 1) per-WG bucket histogram of its contiguous chunk
__global__ __launch_bounds__(256) void k_count(const int4* __restrict__ erow4,
                                               int* __restrict__ cnt_tbl) {
    __shared__ int hist[NBUK1];
    const int t = threadIdx.x, wg = blockIdx.x;
    for (int i = t; i < NBUK1; i += 256) hist[i] = 0;
    __syncthreads();
    const int end4 = (wg + 1) * CHUNK4;
    for (int i4 = wg * CHUNK4 + t; i4 < end4; i4 += 256) {
        const int4 r = erow4[i4];
        atomicAdd(&hist[r.x >> 8], 1);
        atomicAdd(&hist[r.y >> 8], 1);
        atomicAdd(&hist[r.z >> 8], 1);
        atomicAdd(&hist[r.w >> 8], 1);
    }
    __syncthreads();
    for (int i = t; i < NBUK1; i += 256) cnt_tbl[wg * NBUK1 + i] = hist[i];
}

// 2) exact offsets: bucket bases + per-(wg,bucket) cursors (single WG)
// thread t owns buckets 2t and 2t+1
__global__ __launch_bounds__(256) void k_scan2(const int* __restrict__ cnt_tbl,
                                               int* __restrict__ off_tbl,
                                               int* __restrict__ boff) {
    __shared__ int sd[256];
    const int t = threadIdx.x;
    const int b0 = 2 * t, b1 = 2 * t + 1;
    int tot = 0;
    if (b0 < NBUK1) for (int wg = 0; wg < NWG; ++wg) tot += cnt_tbl[wg * NBUK1 + b0];
    if (b1 < NBUK1) for (int wg = 0; wg < NWG; ++wg) tot += cnt_tbl[wg * NBUK1 + b1];
    sd[t] = tot;
    __syncthreads();
    for (int off = 1; off < 256; off <<= 1) {
        int a = sd[t];
        int b = (t >= off) ? sd[t - off] : 0;
        __syncthreads();
        sd[t] = a + b;
        __syncthreads();
    }
    int run = sd[t] - tot;   // exclusive base for this thread's pair
    if (b0 < NBUK1) {
        boff[b0] = run;
        for (int wg = 0; wg < NWG; ++wg) {
            off_tbl[wg * NBUK1 + b0] = run;
            run += cnt_tbl[wg * NBUK1 + b0];
        }
    }
    if (b1 < NBUK1) {
        boff[b1] = run;
        for (int wg = 0; wg < NWG; ++wg) {
            off_tbl[wg * NBUK1 + b1] = run;
            run += cnt_tbl[wg * NBUK1 + b1];
        }
    }
    if (t == 255) boff[NBUK1] = NE;
}

// 3) scatter into exact per-WG contiguous runs (single-WG-owned lines)
__global__ __launch_bounds__(256) void k_place(const int4* __restrict__ erow4,
                                               const int4* __restrict__ ecol4,
                                               const float4* __restrict__ eval4,
                                               const int* __restrict__ off_tbl,
                                               uint2* __restrict__ tmp) {
    __shared__ int cur[NBUK1];
    const int t = threadIdx.x, wg = blockIdx.x;
    for (int i = t; i < NBUK1; i += 256) cur[i] = off_tbl[wg * NBUK1 + i];
    __syncthreads();
    const int end4 = (wg + 1) * CHUNK4;
    for (int i4 = wg * CHUNK4 + t; i4 < end4; i4 += 256) {
        const int4 r = erow4[i4];
        const int4 c = ecol4[i4];
        const float4 v = eval4[i4];
        int p;
        p = atomicAdd(&cur[r.x >> 8], 1);
        tmp[p] = make_uint2(((unsigned)(r.x & 255) << 17) | (unsigned)c.x, __float_as_uint(v.x));
        p = atomicAdd(&cur[r.y >> 8], 1);
        tmp[p] = make_uint2(((unsigned)(r.y & 255) << 17) | (unsigned)c.y, __float_as_uint(v.y));
        p = atomicAdd(&cur[r.z >> 8], 1);
        tmp[p] = make_uint2(((unsigned)(r.z & 255) << 17) | (unsigned)c.z, __float_as_uint(v.z));
        p = atomicAdd(&cur[r.w >> 8], 1);
        tmp[p] = make_uint2(((unsigned)(r.w & 255) << 17) | (unsigned)c.w, __float_as_uint(v.w));
    }
}

// 4) one WG per coarse bucket: LDS-staged hist+scan -> row_start, reorder to final CSR
__global__ __launch_bounds__(256) void k_sort2(const uint2* __restrict__ tmp,
                                               const int* __restrict__ boff,
                                               uint2* __restrict__ recs,
                                               int* __restrict__ row_start) {
    __shared__ uint2 sbuf[SORT_CAP];   // 72 KB staging
    __shared__ int hist[ROWS_B];
    __shared__ int cur[ROWS_B];
    __shared__ int sd[256];
    const int b = blockIdx.x, t = threadIdx.x;
    const int base = boff[b];
    const int n = boff[b + 1] - base;
    hist[t] = 0;
    __syncthreads();
    for (int i = t; i < n; i += 256) {
        const uint2 rc = tmp[base + i];
        if (i < SORT_CAP) sbuf[i] = rc;
        atomicAdd(&hist[rc.x >> 17], 1);
    }
    __syncthreads();
    const int hv = hist[t];
    sd[t] = hv;
    __syncthreads();
    for (int off = 1; off < 256; off <<= 1) {
        int a = sd[t];
        int bb = (t >= off) ? sd[t - off] : 0;
        __syncthreads();
        sd[t] = a + bb;
        __syncthreads();
    }
    const int excl = sd[t] - hv;          // exclusive within bucket
    cur[t] = base + excl;
    const int gr = b * ROWS_B + t;
    if (gr < NN) row_start[gr] = base + excl;
    if (b == NBUK1 - 1 && t == 0) row_start[NN] = NE;
    __syncthreads();
    for (int i = t; i < n; i += 256) {
        const uint2 rc = (i < SORT_CAP) ? sbuf[i] : tmp[base + i];
        const int lr = rc.x >> 17;
        const int pos = atomicAdd(&cur[lr], 1);
        recs[pos] = make_uint2(rc.x & 0x1FFFFu, rc.y);
    }
}

// ---------------- SpMM1 + bias + ReLU + GEMM2 fused ----------------
// xw1 bf16 [NN,128]; per wave: gather-accumulate h row, then hw4 = bf16(relu(h)@W4).
// W4 staged padded in LDS: elem (k,c) at 16k+c+16*(k>>5)   (2-way banks on read)
// h row staged per-wave in LDS: elem k at k+(k>>5)          (conflict-free read)
__global__ __launch_bounds__(256) void k_spmm1(const unsigned int* __restrict__ xw1u,
                                               const int* __restrict__ row_start,
                                               const uint2* __restrict__ recs,
                                               const float* __restrict__ b1,
                                               const float* __restrict__ W4,
                                               unsigned short* __restrict__ hw4) {
    __shared__ float w4p[2048 + 48];
    __shared__ float hrow[4][132];
    const int t = threadIdx.x;
    for (int i = t; i < 2048; i += 256) {
        const int k = i >> 4;
        w4p[i + 16 * (k >> 5)] = W4[i];
    }
    __syncthreads();

    const int wid = (blockIdx.x * 256 + t) >> 6;   // one wave per node (NN%4==0)
    const int lane = t & 63;
    if (wid >= NN) return;
    const int s = row_start[wid], e = row_start[wid + 1];
    float2 acc = make_float2(0.f, 0.f);
    for (int base = s; base < e; base += 64) {
        const int n = min(64, e - base);
        uint2 rv = make_uint2(0u, 0u);
        if (lane < n) rv = recs[base + lane];
        int j = 0;
        for (; j + 2 <= n; j += 2) {
            const int c0 = __shfl((int)rv.x, j), c1 = __shfl((int)rv.x, j + 1);
            const float v0 = __uint_as_float((unsigned int)__shfl((int)rv.y, j));
            const float v1 = __uint_as_float((unsigned int)__shfl((int)rv.y, j + 1));
            const unsigned int u0 = xw1u[c0 * 64 + lane];
            const unsigned int u1 = xw1u[c1 * 64 + lane];
            acc.x = fmaf(v0, __uint_as_float(u0 << 16), acc.x);
            acc.y = fmaf(v0, __uint_as_float(u0 & 0xffff0000u), acc.y);
            acc.x = fmaf(v1, __uint_as_float(u1 << 16), acc.x);
            acc.y = fmaf(v1, __uint_as_float(u1 & 0xffff0000u), acc.y);
        }
        if (j < n) {
            const int c0 = __shfl((int)rv.x, j);
            const float v0 = __uint_as_float((unsigned int)__shfl((int)rv.y, j));
            const unsigned int u0 = xw1u[c0 * 64 + lane];
            acc.x = fmaf(v0, __uint_as_float(u0 << 16), acc.x);
            acc.y = fmaf(v0, __uint_as_float(u0 & 0xffff0000u), acc.y);
        }
    }
    const float2 bb = *(const float2*)(b1 + (lane << 1));
    acc.x = fmaxf(acc.x + bb.x, 0.f);
    acc.y = fmaxf(acc.y + bb.y, 0.f);

    // ---- fused GEMM2 epilogue: hw4[wid][c] = sum_k h[k]*W4[k][c] ----
    const int wv = t >> 6;
    // store h[2*lane], h[2*lane+1] at padded word 2*lane + (lane>>4)  (wave-private)
    *(float2*)(&hrow[wv][2 * lane + (lane >> 4)]) = acc;
    const int q = lane >> 4, c = lane & 15;
    float p = 0.f;
#pragma unroll
    for (int j = 0; j < 32; ++j) {
        const int k = 32 * q + j;
        p = fmaf(hrow[wv][k + q], w4p[16 * k + c + 16 * q], p);
    }
    p += __shfl_xor(p, 16);
    p += __shfl_xor(p, 32);
    if (lane < 16) hw4[wid * 16 + c] = f2bf(p);
}

// ---------------- SpMM2 + bias + log_softmax ----------------
// hw4 is bf16 [NN,16] = 32B rows (3.2 MB: mostly L2-resident)
__global__ __launch_bounds__(256) void k_spmm2(const __hip_bfloat16* __restrict__ hw4,
                                               const int* __restrict__ row_start,
                                               const uint2* __restrict__ recs,
                                               const float* __restrict__ b4,
                                               float* __restrict__ out) {
    const int wid = (blockIdx.x * 256 + threadIdx.x) >> 6;   // one wave per node
    const int lane = threadIdx.x & 63;
    if (wid >= NN) return;
    const int f = lane & 15, g = lane >> 4;   // 4 edges in parallel
    const int s = row_start[wid], e = row_start[wid + 1];
    float acc = 0.f;
    for (int base = s + g; base < e; base += 4) {
        const uint2 rv = recs[base];
        const int c = (int)rv.x;
        const float v = __uint_as_float(rv.y);
        const float a = __uint_as_float(((unsigned int)*(const unsigned short*)(hw4 + c * 16 + f)) << 16);
        acc = fmaf(v, a, acc);
    }
    acc += __shfl_xor(acc, 16);
    acc += __shfl_xor(acc, 32);
    acc += b4[f];
    float m = acc;
#pragma unroll
    for (int off = 1; off < 16; off <<= 1) m = fmaxf(m, __shfl_xor(m, off));
    const float ex = __expf(acc - m);
    float sum = ex;
#pragma unroll
    for (int off = 1; off < 16; off <<= 1) sum += __shfl_xor(sum, off);
    const float res = acc - m - __logf(sum);
    if (lane < 16) out[wid * 16 + f] = res;
}

extern "C" void kernel_launch(void* const* d_in, const int* in_sizes, int n_in,
                              void* d_out, int out_size, void* d_ws, size_t ws_size,
                              hipStream_t stream) {
    const float* x        = (const float*)d_in[0];
    const float* edge_val = (const float*)d_in[1];
    const float* W1       = (const float*)d_in[2];
    const float* b1       = (const float*)d_in[3];
    const float* W4       = (const float*)d_in[4];
    const float* b4       = (const float*)d_in[5];
    const int*   edge_row = (const int*)d_in[6];
    const int*   edge_col = (const int*)d_in[7];
    float* out = (float*)d_out;

    char* ws = (char*)d_ws;
    size_t off = 0;
    auto alloc = [&](size_t bytes) -> void* {
        void* p = ws + off;
        off = (off + bytes + 255) & ~(size_t)255;
        return p;
    };
    unsigned short* xw1 = (unsigned short*)alloc((size_t)NN * 128 * 2);  // 25.6 MB bf16
    unsigned short* hw4 = (unsigned short*)alloc((size_t)NN * 16 * 2);   // 3.2 MB bf16
    int*   cnt_tbl      = (int*)alloc((size_t)NWG * NBUK1 * 4);          // 400 KB
    int*   off_tbl      = (int*)alloc((size_t)NWG * NBUK1 * 4);          // 400 KB
    int*   boff         = (int*)alloc((size_t)(NBUK1 + 1) * 4);
    int*   row_start    = (int*)alloc((size_t)(NN + 1) * 4);
    uint2* tmp          = (uint2*)alloc((size_t)NE * 8);                 // 25.6 MB
    uint2* recs         = (uint2*)alloc((size_t)NE * 8);                 // 25.6 MB

    k_gemm1<<<NN / 32, 256, 0, stream>>>(x, W1, xw1);
    k_count<<<NWG, 256, 0, stream>>>((const int4*)edge_row, cnt_tbl);
    k_scan2<<<1, 256, 0, stream>>>(cnt_tbl, off_tbl, boff);
    k_place<<<NWG, 256, 0, stream>>>((const int4*)edge_row, (const int4*)edge_col,
                                     (const float4*)edge_val, off_tbl, tmp);
    k_sort2<<<NBUK1, 256, 0, stream>>>(tmp, boff, recs, row_start);
    k_spmm1<<<(NN + 3) / 4, 256, 0, stream>>>((const unsigned int*)xw1, row_start, recs,
                                              b1, W4, hw4);
    k_spmm2<<<(NN + 3) / 4, 256, 0, stream>>>((const __hip_bfloat16*)hw4, row_start, recs, b4, out);
}

// Round 8
// 503.871 us; speedup vs baseline: 1.0645x; 1.0645x over previous
//
#include <hip/hip_runtime.h>
#include <hip/hip_bf16.h>

// Problem constants (fixed by reference)
constexpr int NN = 100000;   // nodes
constexpr int NE = 3200000;  // edges
constexpr int NWG = 256;               // chunks for count/place
constexpr int CHUNK = NE / NWG;        // 12500 edges per WG
constexpr int CHUNK4 = CHUNK / 4;      // 3125 int4s per WG
constexpr int ROWS_B = 256;            // rows per coarse bucket
constexpr int NBUK1 = (NN + ROWS_B - 1) / ROWS_B;  // 391 coarse buckets (rows >> 8)
constexpr int SORT_CAP = 9216;         // LDS staging cap (avg 8192, sigma~90)

__device__ __forceinline__ unsigned short f2bf(float f) {
    unsigned int u = __float_as_uint(f);
    unsigned int r = (u + 0x7fffu + ((u >> 16) & 1u)) >> 16;   // RNE
    return (unsigned short)r;
}

// ---------------- GEMM1: xw1 = bf16(x @ W1)  [NN,128]x[128,128] ----------------
__global__ __launch_bounds__(256) void k_gemm1(const float* __restrict__ x,
                                               const float* __restrict__ W,
                                               unsigned short* __restrict__ y) {
    __shared__ float ws_[128 * 128];   // 64 KB: whole W1
    __shared__ float xs[8][128];       // 8 staged rows
    const int t = threadIdx.x;
    for (int i = t; i < 128 * 128; i += 256) ws_[i] = W[i];

    const int rowg = t >> 5;          // 0..7 (row within sub-tile)
    const int cq   = (t & 31) * 4;    // 4 output cols
    const int row0 = blockIdx.x * 32;

    for (int rs = 0; rs < 32; rs += 8) {
        __syncthreads();
        {   // stage 8 rows (1024 floats) as 256 float4s
            const int r  = t >> 5;
            const int c4 = (t & 31) * 4;
            const int row = row0 + rs + r;
            float4 val = (row < NN) ? *(const float4*)(x + row * 128 + c4)
                                    : make_float4(0.f, 0.f, 0.f, 0.f);
            *(float4*)(&xs[r][c4]) = val;
        }
        __syncthreads();
        float4 acc = make_float4(0.f, 0.f, 0.f, 0.f);
#pragma unroll
        for (int k = 0; k < 128; ++k) {
            const float xv = xs[rowg][k];
            const float4 wv = *(const float4*)(&ws_[k * 128 + cq]);
            acc.x = fmaf(xv, wv.x, acc.x);
            acc.y = fmaf(xv, wv.y, acc.y);
            acc.z = fmaf(xv, wv.z, acc.z);
            acc.w = fmaf(xv, wv.w, acc.w);
        }
        const int row = row0 + rs + rowg;
        if (row < NN) {
            ushort4 o;
            o.x = f2bf(acc.x); o.y = f2bf(acc.y);
            o.z = f2bf(acc.z); o.w = f2bf(acc.w);
            *(ushort4*)(y + row * 128 + cq) = o;   // 8B store
        }
    }
}

// ---------------- CSR build: WG-exclusive counting sort ----------------
// coarse bucket = row >> 8 (256 rows). tmp record: x = (lrow<<17)|col, y = val.

// 1) per-WG bucket histogram of its contiguous chunk
__global__ __launch_bounds__(256) void k_count(const int4* __restrict__ erow4,
                                               int* __restrict__ cnt_tbl) {
    __shared__ int hist[NBUK1];
    const int t = threadIdx.x, wg = blockIdx.x;
    for (int i = t; i < NBUK1; i += 256) hist[i] = 0;
    __syncthreads();
    const int end4 = (wg + 1) * CHUNK4;
    for (int i4 = wg * CHUNK4 + t; i4 < end4; i4 += 256) {
        const int4 r = erow4[i4];
        atomicAdd(&hist[r.x >> 8], 1);
        atomicAdd(&hist[r.y >> 8], 1);
        atomicAdd(&hist[r.z >> 8], 1);
        atomicAdd(&hist[r.w >> 8], 1);
    }
    __syncthreads();
    for (int i = t; i < NBUK1; i += 256) cnt_tbl[wg * NBUK1 + i] = hist[i];
}

// 2) exact offsets: bucket bases + per-(wg,bucket) cursors (single WG)
// thread t owns buckets 2t and 2t+1
__global__ __launch_bounds__(256) void k_scan2(const int* __restrict__ cnt_tbl,
                                               int* __restrict__ off_tbl,
                                               int* __restrict__ boff) {
    __shared__ int sd[256];
    const int t = threadIdx.x;
    const int b0 = 2 * t, b1 = 2 * t + 1;
    int tot = 0;
    if (b0 < NBUK1) for (int wg = 0; wg < NWG; ++wg) tot += cnt_tbl[wg * NBUK1 + b0];
    if (b1 < NBUK1) for (int wg = 0; wg < NWG; ++wg) tot += cnt_tbl[wg * NBUK1 + b1];
    sd[t] = tot;
    __syncthreads();
    for (int off = 1; off < 256; off <<= 1) {
        int a = sd[t];
        int b = (t >= off) ? sd[t - off] : 0;
        __syncthreads();
        sd[t] = a + b;
        __syncthreads();
    }
    int run = sd[t] - tot;   // exclusive base for this thread's pair
    if (b0 < NBUK1) {
        boff[b0] = run;
        for (int wg = 0; wg < NWG; ++wg) {
            off_tbl[wg * NBUK1 + b0] = run;
            run += cnt_tbl[wg * NBUK1 + b0];
        }
    }
    if (b1 < NBUK1) {
        boff[b1] = run;
        for (int wg = 0; wg < NWG; ++wg) {
            off_tbl[wg * NBUK1 + b1] = run;
            run += cnt_tbl[wg * NBUK1 + b1];
        }
    }
    if (t == 255) boff[NBUK1] = NE;
}

// 3) scatter into exact per-WG contiguous runs (single-WG-owned lines)
__global__ __launch_bounds__(256) void k_place(const int4* __restrict__ erow4,
                                               const int4* __restrict__ ecol4,
                                               const float4* __restrict__ eval4,
                                               const int* __restrict__ off_tbl,
                                               uint2* __restrict__ tmp) {
    __shared__ int cur[NBUK1];
    const int t = threadIdx.x, wg = blockIdx.x;
    for (int i = t; i < NBUK1; i += 256) cur[i] = off_tbl[wg * NBUK1 + i];
    __syncthreads();
    const int end4 = (wg + 1) * CHUNK4;
    for (int i4 = wg * CHUNK4 + t; i4 < end4; i4 += 256) {
        const int4 r = erow4[i4];
        const int4 c = ecol4[i4];
        const float4 v = eval4[i4];
        int p;
        p = atomicAdd(&cur[r.x >> 8], 1);
        tmp[p] = make_uint2(((unsigned)(r.x & 255) << 17) | (unsigned)c.x, __float_as_uint(v.x));
        p = atomicAdd(&cur[r.y >> 8], 1);
        tmp[p] = make_uint2(((unsigned)(r.y & 255) << 17) | (unsigned)c.y, __float_as_uint(v.y));
        p = atomicAdd(&cur[r.z >> 8], 1);
        tmp[p] = make_uint2(((unsigned)(r.z & 255) << 17) | (unsigned)c.z, __float_as_uint(v.z));
        p = atomicAdd(&cur[r.w >> 8], 1);
        tmp[p] = make_uint2(((unsigned)(r.w & 255) << 17) | (unsigned)c.w, __float_as_uint(v.w));
    }
}

// 4) one WG per coarse bucket: LDS-staged hist+scan -> row_start, reorder to final CSR
__global__ __launch_bounds__(256) void k_sort2(const uint2* __restrict__ tmp,
                                               const int* __restrict__ boff,
                                               uint2* __restrict__ recs,
                                               int* __restrict__ row_start) {
    __shared__ uint2 sbuf[SORT_CAP];   // 72 KB staging
    __shared__ int hist[ROWS_B];
    __shared__ int cur[ROWS_B];
    __shared__ int sd[256];
    const int b = blockIdx.x, t = threadIdx.x;
    const int base = boff[b];
    const int n = boff[b + 1] - base;
    hist[t] = 0;
    __syncthreads();
    for (int i = t; i < n; i += 256) {
        const uint2 rc = tmp[base + i];
        if (i < SORT_CAP) sbuf[i] = rc;
        atomicAdd(&hist[rc.x >> 17], 1);
    }
    __syncthreads();
    const int hv = hist[t];
    sd[t] = hv;
    __syncthreads();
    for (int off = 1; off < 256; off <<= 1) {
        int a = sd[t];
        int bb = (t >= off) ? sd[t - off] : 0;
        __syncthreads();
        sd[t] = a + bb;
        __syncthreads();
    }
    const int excl = sd[t] - hv;          // exclusive within bucket
    cur[t] = base + excl;
    const int gr = b * ROWS_B + t;
    if (gr < NN) row_start[gr] = base + excl;
    if (b == NBUK1 - 1 && t == 0) row_start[NN] = NE;
    __syncthreads();
    for (int i = t; i < n; i += 256) {
        const uint2 rc = (i < SORT_CAP) ? sbuf[i] : tmp[base + i];
        const int lr = rc.x >> 17;
        const int pos = atomicAdd(&cur[lr], 1);
        recs[pos] = make_uint2(rc.x & 0x1FFFFu, rc.y);
    }
}

// ---------------- SpMM1 + bias + ReLU + GEMM2 fused ----------------
// Wave per node. lane = (g,f): g = lane>>4 owns edges s+g, s+g+4, ...;
// f = lane&15 covers feats [8f, 8f+8) via one dwordx4 per edge. No shfl in loop.
// Cross-group combine: shfl_xor(16,32). Epilogue: hw4 = bf16(relu(h)@W4).
// hrow layout: elem k at (k>>3)*9 + (k&7)  -> conflict-free writes, broadcast reads.
// W4 staged padded: elem (k,c) at 16k+c+16*(k>>5)  -> 2-way banks (free).
__global__ __launch_bounds__(256) void k_spmm1(const uint4* __restrict__ xw1q,
                                               const int* __restrict__ row_start,
                                               const uint2* __restrict__ recs,
                                               const float4* __restrict__ b1q,
                                               const float* __restrict__ W4,
                                               unsigned short* __restrict__ hw4) {
    __shared__ float w4p[2048 + 48];
    __shared__ float hrow[4][144];
    const int t = threadIdx.x;
    for (int i = t; i < 2048; i += 256) {
        const int k = i >> 4;
        w4p[i + 16 * (k >> 5)] = W4[i];
    }
    __syncthreads();

    const int wid = (blockIdx.x * 256 + t) >> 6;   // one wave per node (NN%4==0)
    if (wid >= NN) return;
    const int lane = t & 63;
    const int g = lane >> 4;       // edge slot
    const int f = lane & 15;       // feat block
    const int s = row_start[wid], e = row_start[wid + 1];
    float a0 = 0.f, a1 = 0.f, a2 = 0.f, a3 = 0.f, a4 = 0.f, a5 = 0.f, a6 = 0.f, a7 = 0.f;
    for (int base = s + g; base < e; base += 4) {
        const uint2 rv = recs[base];
        const int c = (int)rv.x;
        const float v = __uint_as_float(rv.y);
        const uint4 u = xw1q[c * 16 + f];
        a0 = fmaf(v, __uint_as_float(u.x << 16), a0);
        a1 = fmaf(v, __uint_as_float(u.x & 0xffff0000u), a1);
        a2 = fmaf(v, __uint_as_float(u.y << 16), a2);
        a3 = fmaf(v, __uint_as_float(u.y & 0xffff0000u), a3);
        a4 = fmaf(v, __uint_as_float(u.z << 16), a4);
        a5 = fmaf(v, __uint_as_float(u.z & 0xffff0000u), a5);
        a6 = fmaf(v, __uint_as_float(u.w << 16), a6);
        a7 = fmaf(v, __uint_as_float(u.w & 0xffff0000u), a7);
    }
    a0 += __shfl_xor(a0, 16); a0 += __shfl_xor(a0, 32);
    a1 += __shfl_xor(a1, 16); a1 += __shfl_xor(a1, 32);
    a2 += __shfl_xor(a2, 16); a2 += __shfl_xor(a2, 32);
    a3 += __shfl_xor(a3, 16); a3 += __shfl_xor(a3, 32);
    a4 += __shfl_xor(a4, 16); a4 += __shfl_xor(a4, 32);
    a5 += __shfl_xor(a5, 16); a5 += __shfl_xor(a5, 32);
    a6 += __shfl_xor(a6, 16); a6 += __shfl_xor(a6, 32);
    a7 += __shfl_xor(a7, 16); a7 += __shfl_xor(a7, 32);

    const float4 bA = b1q[2 * f], bB = b1q[2 * f + 1];
    a0 = fmaxf(a0 + bA.x, 0.f); a1 = fmaxf(a1 + bA.y, 0.f);
    a2 = fmaxf(a2 + bA.z, 0.f); a3 = fmaxf(a3 + bA.w, 0.f);
    a4 = fmaxf(a4 + bB.x, 0.f); a5 = fmaxf(a5 + bB.y, 0.f);
    a6 = fmaxf(a6 + bB.z, 0.f); a7 = fmaxf(a7 + bB.w, 0.f);

    // ---- fused GEMM2 epilogue ----
    const int wv = t >> 6;
    if (g == 0) {   // 16 lanes write 8 floats each at stride-9 blocks (conflict-free)
        float* hb = &hrow[wv][9 * f];
        hb[0] = a0; hb[1] = a1; hb[2] = a2; hb[3] = a3;
        hb[4] = a4; hb[5] = a5; hb[6] = a6; hb[7] = a7;
    }
    // wave-private LDS: compiler inserts lgkmcnt wait; no barrier needed
    const int q = g, c = f;   // quarter q dots k in [32q,32q+32)
    float p = 0.f;
#pragma unroll
    for (int j = 0; j < 32; ++j) {
        const int k = 32 * q + j;
        p = fmaf(hrow[wv][(k >> 3) * 9 + (k & 7)], w4p[528 * q + 16 * j + c], p);
    }
    p += __shfl_xor(p, 16);
    p += __shfl_xor(p, 32);
    if (lane < 16) hw4[wid * 16 + c] = f2bf(p);
}

// ---------------- SpMM2 + bias + log_softmax ----------------
// Wave per node. lane = (g,f2): g = lane>>3 owns edges s+g, s+g+8, ...;
// f2 = lane&7 covers feats {2f2, 2f2+1} via one dword per edge. No shfl in loop.
__global__ __launch_bounds__(256) void k_spmm2(const unsigned int* __restrict__ hw4u,
                                               const int* __restrict__ row_start,
                                               const uint2* __restrict__ recs,
                                               const float* __restrict__ b4,
                                               float* __restrict__ out) {
    const int wid = (blockIdx.x * 256 + threadIdx.x) >> 6;   // one wave per node
    if (wid >= NN) return;
    const int lane = threadIdx.x & 63;
    const int g = lane >> 3;      // edge slot 0..7
    const int f2 = lane & 7;      // uint index (feats 2f2, 2f2+1)
    const int s = row_start[wid], e = row_start[wid + 1];
    float ax = 0.f, ay = 0.f;
    for (int base = s + g; base < e; base += 8) {
        const uint2 rv = recs[base];
        const int c = (int)rv.x;
        const float v = __uint_as_float(rv.y);
        const unsigned int u = hw4u[c * 8 + f2];
        ax = fmaf(v, __uint_as_float(u << 16), ax);
        ay = fmaf(v, __uint_as_float(u & 0xffff0000u), ay);
    }
    ax += __shfl_xor(ax, 8);  ay += __shfl_xor(ay, 8);
    ax += __shfl_xor(ax, 16); ay += __shfl_xor(ay, 16);
    ax += __shfl_xor(ax, 32); ay += __shfl_xor(ay, 32);
    const float2 bb = *(const float2*)(b4 + 2 * f2);
    ax += bb.x; ay += bb.y;
    float m = fmaxf(ax, ay);
    m = fmaxf(m, __shfl_xor(m, 1));
    m = fmaxf(m, __shfl_xor(m, 2));
    m = fmaxf(m, __shfl_xor(m, 4));
    float sum = __expf(ax - m) + __expf(ay - m);
    sum += __shfl_xor(sum, 1);
    sum += __shfl_xor(sum, 2);
    sum += __shfl_xor(sum, 4);
    const float lse = m + __logf(sum);
    if (g == 0) *(float2*)(out + wid * 16 + 2 * f2) = make_float2(ax - lse, ay - lse);
}

extern "C" void kernel_launch(void* const* d_in, const int* in_sizes, int n_in,
                              void* d_out, int out_size, void* d_ws, size_t ws_size,
                              hipStream_t stream) {
    const float* x        = (const float*)d_in[0];
    const float* edge_val = (const float*)d_in[1];
    const float* W1       = (const float*)d_in[2];
    const float* b1       = (const float*)d_in[3];
    const float* W4       = (const float*)d_in[4];
    const float* b4       = (const float*)d_in[5];
    const int*   edge_row = (const int*)d_in[6];
    const int*   edge_col = (const int*)d_in[7];
    float* out = (float*)d_out;

    char* ws = (char*)d_ws;
    size_t off = 0;
    auto alloc = [&](size_t bytes) -> void* {
        void* p = ws + off;
        off = (off + bytes + 255) & ~(size_t)255;
        return p;
    };
    unsigned short* xw1 = (unsigned short*)alloc((size_t)NN * 128 * 2);  // 25.6 MB bf16
    unsigned short* hw4 = (unsigned short*)alloc((size_t)NN * 16 * 2);   // 3.2 MB bf16
    int*   cnt_tbl      = (int*)alloc((size_t)NWG * NBUK1 * 4);          // 400 KB
    int*   off_tbl      = (int*)alloc((size_t)NWG * NBUK1 * 4);          // 400 KB
    int*   boff         = (int*)alloc((size_t)(NBUK1 + 1) * 4);
    int*   row_start    = (int*)alloc((size_t)(NN + 1) * 4);
    uint2* tmp          = (uint2*)alloc((size_t)NE * 8);                 // 25.6 MB
    uint2* recs         = (uint2*)alloc((size_t)NE * 8);                 // 25.6 MB

    k_gemm1<<<NN / 32, 256, 0, stream>>>(x, W1, xw1);
    k_count<<<NWG, 256, 0, stream>>>((const int4*)edge_row, cnt_tbl);
    k_scan2<<<1, 256, 0, stream>>>(cnt_tbl, off_tbl, boff);
    k_place<<<NWG, 256, 0, stream>>>((const int4*)edge_row, (const int4*)edge_col,
                                     (const float4*)edge_val, off_tbl, tmp);
    k_sort2<<<NBUK1, 256, 0, stream>>>(tmp, boff, recs, row_start);
    k_spmm1<<<(NN + 3) / 4, 256, 0, stream>>>((const uint4*)xw1, row_start, recs,
                                              (const float4*)b1, W4, hw4);
    k_spmm2<<<(NN + 3) / 4, 256, 0, stream>>>((const unsigned int*)hw4, row_start, recs,
                                              b4, out);
}